// Round 2
// baseline (1137.823 us; speedup 1.0000x reference)
//
#include <hip/hip_runtime.h>
#include <stdint.h>

typedef unsigned short u16;
typedef unsigned int u32;
typedef __bf16 bf16x8 __attribute__((ext_vector_type(8)));
typedef float f32x4 __attribute__((ext_vector_type(4)));

#define N_NODES 65536
#define N_EDGES 131072
#define N_GRAPHS 2048

static __device__ __forceinline__ float bf2f(u16 u) {
  union { u32 u; float f; } v; v.u = ((u32)u) << 16; return v.f;
}
static __device__ __forceinline__ u16 f2bf(float f) {
  union { float f; u32 u; } v; v.f = f;
  u32 r = v.u + 0x7fffu + ((v.u >> 16) & 1u);
  return (u16)(r >> 16);
}
static __device__ __forceinline__ void gl16(const void* g, void* l) {
  __builtin_amdgcn_global_load_lds(
      (__attribute__((address_space(1))) void*)(g),
      (__attribute__((address_space(3))) void*)(l), 16, 0, 0);
}

// ---------------------------------------------------------------------------
// bf16 GEMM, C[M][N] = epi(A[M][K] @ W[N][K]^T + bias).  128x128 tile, BK=32,
// 4 waves (2x2), each wave 64x64 via 4x4 mfma_f32_16x16x32_bf16 fragments.
// EPI 0: relu -> bf16.  EPI 1: relu -> bn affine (scale/shift) -> bf16.
// ---------------------------------------------------------------------------
template <int EPI>
__global__ __launch_bounds__(256) void gemm_bt(
    const u16* __restrict__ A, const u16* __restrict__ W,
    const float* __restrict__ bias, const float* __restrict__ scale,
    const float* __restrict__ shift, u16* __restrict__ Cp,
    int K, int ldc, int coff) {
  __shared__ u16 As[128 * 32];
  __shared__ u16 Bs[128 * 32];
  const int bm = blockIdx.y * 128;
  const int bn = blockIdx.x * 128;
  const int tid = threadIdx.x;
  const int lane = tid & 63;
  const int wid = tid >> 6;
  const int wr = wid >> 1, wc = wid & 1;
  const int lg = lane >> 4, lr = lane & 15;

  f32x4 acc[4][4];
#pragma unroll
  for (int i = 0; i < 4; ++i)
#pragma unroll
    for (int j = 0; j < 4; ++j) acc[i][j] = (f32x4){0.f, 0.f, 0.f, 0.f};

  const int srow = tid >> 2;
  const int c8 = (tid & 3) * 8;
  const u16* Ag0 = A + (size_t)(bm + srow) * K + c8;
  const u16* Ag1 = A + (size_t)(bm + 64 + srow) * K + c8;
  const u16* Wg0 = W + (size_t)(bn + srow) * K + c8;
  const u16* Wg1 = W + (size_t)(bn + 64 + srow) * K + c8;
  u16* lA0 = &As[tid * 8];
  u16* lA1 = &As[2048 + tid * 8];
  u16* lB0 = &Bs[tid * 8];
  u16* lB1 = &Bs[2048 + tid * 8];

  for (int k0 = 0; k0 < K; k0 += 32) {
    gl16(Ag0 + k0, lA0);
    gl16(Ag1 + k0, lA1);
    gl16(Wg0 + k0, lB0);
    gl16(Wg1 + k0, lB1);
    __syncthreads();  // drains vmcnt (global_load_lds) per compiler semantics
    bf16x8 af[4], bfv[4];
#pragma unroll
    for (int i = 0; i < 4; ++i)
      af[i] = *(const bf16x8*)&As[(wr * 64 + i * 16 + lr) * 32 + lg * 8];
#pragma unroll
    for (int j = 0; j < 4; ++j)
      bfv[j] = *(const bf16x8*)&Bs[(wc * 64 + j * 16 + lr) * 32 + lg * 8];
#pragma unroll
    for (int i = 0; i < 4; ++i)
#pragma unroll
      for (int j = 0; j < 4; ++j)
        acc[i][j] = __builtin_amdgcn_mfma_f32_16x16x32_bf16(af[i], bfv[j],
                                                            acc[i][j], 0, 0, 0);
    __syncthreads();
  }

#pragma unroll
  for (int i = 0; i < 4; ++i) {
#pragma unroll
    for (int j = 0; j < 4; ++j) {
#pragma unroll
      for (int r = 0; r < 4; ++r) {
        const int grow = bm + wr * 64 + i * 16 + lg * 4 + r;
        const int gcol = bn + wc * 64 + j * 16 + lr;
        float v = acc[i][j][r] + bias[gcol];
        v = fmaxf(v, 0.f);
        if (EPI == 1) v = v * scale[gcol] + shift[gcol];
        Cp[(size_t)grow * ldc + coff + gcol] = f2bf(v);
      }
    }
  }
}

// ---------------------------------------------------------------------------
// Edge phase: agg[dst][c] += relu(h[src][h_coff+c] + edge_attr @ ew^T + eb).
// ew/eb are pre-sliced to the channel block. 8 edges per block; weights staged
// in LDS.  HF32=1: H is f32 (layer-1 input x).  HF32=0: H is bf16.
// ---------------------------------------------------------------------------
template <int HF32>
__global__ void edge_msg(const float* __restrict__ ea, const int* __restrict__ src,
                         const int* __restrict__ dst, const float* __restrict__ ew,
                         const float* __restrict__ eb, const void* __restrict__ Hv,
                         int h_ld, int h_coff, float* __restrict__ agg, int C) {
  __shared__ float ewsh[2560];
  __shared__ float eash[8][10];
  const int tid = threadIdx.x;
  const int bd = blockDim.x;
  const int e0 = blockIdx.x * 8;
  for (int i = tid; i < C * 10; i += bd) ewsh[i] = ew[i];
  if (tid < 80) eash[tid / 10][tid % 10] = ea[(size_t)e0 * 10 + tid];
  __syncthreads();
  if (tid >= C) return;
  const float* wrow = &ewsh[tid * 10];
  const float sum0 = eb[tid];
#pragma unroll
  for (int j = 0; j < 8; ++j) {
    const int e = e0 + j;
    float sum = sum0;
#pragma unroll
    for (int k = 0; k < 10; ++k) sum += eash[j][k] * wrow[k];
    const int s = src[e], d = dst[e];
    float h = HF32 ? ((const float*)Hv)[(size_t)s * h_ld + h_coff + tid]
                   : bf2f(((const u16*)Hv)[(size_t)s * h_ld + h_coff + tid]);
    float v = fmaxf(h + sum, 0.f);
    atomicAdd(&agg[(size_t)d * C + tid], v);
  }
}

// In-place residual for layers 2/3: HB[:, c0..c0+256) = bf16(f32(HB) + AGG).
// AGG is [N_NODES][256] f32, HB is [N_NODES][512] bf16.
__global__ void add_cvt_ip(const float4* __restrict__ agg, u16* __restrict__ HB,
                           int c0) {
  int i = blockIdx.x * blockDim.x + threadIdx.x;
  if (i >= N_NODES * 64) return;  // 64 float4 per row
  int row = i >> 6, c = (i & 63) << 2;
  float4 va = agg[i];
  uint2* hp = (uint2*)&HB[(size_t)row * 512 + c0 + c];
  uint2 hv = *hp;
  float h0 = bf2f((u16)(hv.x & 0xffffu)), h1 = bf2f((u16)(hv.x >> 16));
  float h2 = bf2f((u16)(hv.y & 0xffffu)), h3 = bf2f((u16)(hv.y >> 16));
  uint2 r;
  r.x = (u32)f2bf(va.x + h0) | ((u32)f2bf(va.y + h1) << 16);
  r.y = (u32)f2bf(va.z + h2) | ((u32)f2bf(va.w + h3) << 16);
  *hp = r;
}

// Layer-1 residual: out[row][0..96) = bf16(agg[row][j] + x[row][j]) (pad 78->96)
__global__ void add_cvt_pad(const float* __restrict__ a, const float* __restrict__ h,
                            u16* __restrict__ out, int rows, int cin, int cout) {
  int idx = blockIdx.x * blockDim.x + threadIdx.x;
  if (idx >= rows * cout) return;
  int rrow = idx / cout, j = idx - rrow * cout;
  out[idx] = (j < cin) ? f2bf(a[(size_t)rrow * cin + j] + h[(size_t)rrow * cin + j])
                       : (u16)0;
}

// f32 -> bf16 with optional column padding (weights, finger)
__global__ void cvt_pad(const float* __restrict__ in, u16* __restrict__ out,
                        int rows, int cin, int cout) {
  int idx = blockIdx.x * blockDim.x + threadIdx.x;
  if (idx >= rows * cout) return;
  int rrow = idx / cout, j = idx - rrow * cout;
  out[idx] = (j < cin) ? f2bf(in[(size_t)rrow * cin + j]) : (u16)0;
}

// BN folded to per-channel affine
__global__ void bn_affine(const float* __restrict__ g, const float* __restrict__ b,
                          const float* __restrict__ m, const float* __restrict__ v,
                          float* __restrict__ scale, float* __restrict__ shift, int n) {
  int i = blockIdx.x * blockDim.x + threadIdx.x;
  if (i < n) {
    float s = g[i] * rsqrtf(v[i] + 1e-5f);
    scale[i] = s;
    shift[i] = b[i] - m[i] * s;
  }
}

// segment starts from sorted batch: start[g] = first node with batch >= g
__global__ void seg_starts(const int* __restrict__ batch, int* __restrict__ start,
                           int n, int ngraphs) {
  int i = blockIdx.x * blockDim.x + threadIdx.x;
  if (i >= n) return;
  int b = batch[i];
  int prev = (i == 0) ? -1 : batch[i - 1];
  for (int g = prev + 1; g <= b; ++g) start[g] = i;
  if (i == n - 1)
    for (int g = b + 1; g <= ngraphs; ++g) start[g] = n;
}

// global_add_pool (block per graph, thread per channel), bf16 in/out
__global__ void pool_sum(const u16* __restrict__ H, const int* __restrict__ start,
                         u16* __restrict__ g) {
  int gi = blockIdx.x, c = threadIdx.x;
  int s = start[gi], e = start[gi + 1];
  float acc = 0.f;
  for (int i = s; i < e; ++i) acc += bf2f(H[(size_t)i * 512 + c]);
  g[gi * 512 + c] = f2bf(acc);
}

// fb3 (relu) + fb4 + sigmoid, one block (64 threads) per graph row
__global__ void fb34(const u16* __restrict__ y2, const float* __restrict__ w3,
                     const float* __restrict__ b3, const float* __restrict__ w4,
                     const float* __restrict__ b4, float* __restrict__ out) {
  __shared__ float yr[128];
  __shared__ float h3[64];
  const int row = blockIdx.x, t = threadIdx.x;
  yr[t] = bf2f(y2[row * 128 + t]);
  yr[t + 64] = bf2f(y2[row * 128 + 64 + t]);
  __syncthreads();
  float s = b3[t];
  const float* w3r = &w3[t * 128];
#pragma unroll 8
  for (int k = 0; k < 128; ++k) s += yr[k] * w3r[k];
  h3[t] = fmaxf(s, 0.f);
  __syncthreads();
  if (t < 2) {
    float s4 = b4[t];
    const float* w4r = &w4[t * 64];
    for (int k = 0; k < 64; ++k) s4 += h3[k] * w4r[k];
    out[row * 2 + t] = 1.f / (1.f + expf(-s4));
  }
}

// ---------------------------------------------------------------------------
#define CDIV(a, b) (((a) + (b)-1) / (b))

extern "C" void kernel_launch(void* const* d_in, const int* in_sizes, int n_in,
                              void* d_out, int out_size, void* d_ws, size_t ws_size,
                              hipStream_t stream) {
  const float* x = (const float*)d_in[0];
  const float* finger = (const float*)d_in[1];
  const float* ea = (const float*)d_in[2];
  const int* eidx = (const int*)d_in[3];
  const int* batch = (const int*)d_in[4];
  const int* esrc = eidx;
  const int* edst = eidx + N_EDGES;

  const float* P[49];
  for (int i = 5; i < 49; ++i) P[i] = (const float*)d_in[i];
  // layer param base indices: l1=5, l2=15, l3=25
  // +0 ew, +1 eb, +2 w1, +3 b1, +4 w2, +5 b2, +6 bng, +7 bnb, +8 bnm, +9 bnv
  const float* fcg_w = P[35]; const float* fcg_b = P[36];
  const float* fp1_w = P[37]; const float* fp1_b = P[38];
  const float* fp2_w = P[39]; const float* fp2_b = P[40];
  const float* fb1_w = P[41]; const float* fb1_b = P[42];
  const float* fb2_w = P[43]; const float* fb2_b = P[44];
  const float* fb3_w = P[45]; const float* fb3_b = P[46];
  const float* fb4_w = P[47]; const float* fb4_b = P[48];

  // ---- workspace layout (~137.7 MB total) ----
  size_t off = 0;
  char* base = (char*)d_ws;
  auto alloc = [&](size_t bytes) -> void* {
    void* p = base + off;
    off = (off + bytes + 255) & ~(size_t)255;
    return p;
  };
  u16* HB = (u16*)alloc((size_t)N_NODES * 512 * 2);     // H / T in-place (bf16)
  char* AGGU = (char*)alloc((size_t)N_NODES * 512 * 2); // AGG f32 [N][256] / UB bf16 [N][512] / head bufs
  u16* w11 = (u16*)alloc(256 * 96 * 2);
  u16* w12 = (u16*)alloc(512 * 256 * 2);
  u16* w21 = (u16*)alloc(512 * 512 * 2);
  u16* w22 = (u16*)alloc(512 * 512 * 2);
  u16* w31 = (u16*)alloc(512 * 512 * 2);
  u16* w32 = (u16*)alloc(512 * 512 * 2);
  u16* wfcg = (u16*)alloc(256 * 512 * 2);
  u16* wfp1 = (u16*)alloc(128 * 1504 * 2);
  u16* wfp2 = (u16*)alloc(256 * 128 * 2);
  u16* wfb1 = (u16*)alloc(256 * 512 * 2);
  u16* wfb2 = (u16*)alloc(128 * 256 * 2);
  float* bnS = (float*)alloc(6 * 512 * 4);
  int* start = (int*)alloc(2049 * 4);
  if (off > ws_size) return;  // workspace insufficient; bail

  float* AGG = (float*)AGGU;           // [N_NODES][256] f32 (layer1: [N][78])
  u16* UB = (u16*)AGGU;                // [N_NODES][512] bf16 (layer1: [N][256])
  // head buffers carved from AGGU (used only after the GNN layers)
  u16* fingb = (u16*)AGGU;                            // 2048*1504  = 6,160,384 B
  u16* gbuf = (u16*)(AGGU + 6160384);                 // 2048*512   = 2,097,152 B
  u16* y0 = (u16*)(AGGU + 8257536);                   // 2048*512   = 2,097,152 B
  u16* fpa = (u16*)(AGGU + 10354688);                 // 2048*128   =   524,288 B
  u16* y1 = (u16*)(AGGU + 10878976);                  // 2048*256   = 1,048,576 B
  u16* y2 = (u16*)(AGGU + 11927552);                  // 2048*128   =   524,288 B

  // ---- parameter prep ----
  cvt_pad<<<CDIV(256 * 96, 256), 256, 0, stream>>>(P[5 + 2], w11, 256, 78, 96);
  cvt_pad<<<CDIV(512 * 256, 256), 256, 0, stream>>>(P[5 + 4], w12, 512, 256, 256);
  cvt_pad<<<CDIV(512 * 512, 256), 256, 0, stream>>>(P[15 + 2], w21, 512, 512, 512);
  cvt_pad<<<CDIV(512 * 512, 256), 256, 0, stream>>>(P[15 + 4], w22, 512, 512, 512);
  cvt_pad<<<CDIV(512 * 512, 256), 256, 0, stream>>>(P[25 + 2], w31, 512, 512, 512);
  cvt_pad<<<CDIV(512 * 512, 256), 256, 0, stream>>>(P[25 + 4], w32, 512, 512, 512);
  cvt_pad<<<CDIV(256 * 512, 256), 256, 0, stream>>>(fcg_w, wfcg, 256, 512, 512);
  cvt_pad<<<CDIV(128 * 1504, 256), 256, 0, stream>>>(fp1_w, wfp1, 128, 1489, 1504);
  cvt_pad<<<CDIV(256 * 128, 256), 256, 0, stream>>>(fp2_w, wfp2, 256, 128, 128);
  cvt_pad<<<CDIV(256 * 512, 256), 256, 0, stream>>>(fb1_w, wfb1, 256, 512, 512);
  cvt_pad<<<CDIV(128 * 256, 256), 256, 0, stream>>>(fb2_w, wfb2, 128, 256, 256);
  for (int l = 0; l < 3; ++l) {
    int pb = 5 + 10 * l;
    bn_affine<<<2, 256, 0, stream>>>(P[pb + 6], P[pb + 7], P[pb + 8], P[pb + 9],
                                     bnS + 1024 * l, bnS + 1024 * l + 512, 512);
  }
  seg_starts<<<CDIV(N_NODES, 256), 256, 0, stream>>>(batch, start, N_NODES, N_GRAPHS);

  // ---- layer 1 (Cin=78) ----
  hipMemsetAsync(AGG, 0, (size_t)N_NODES * 78 * 4, stream);
  edge_msg<1><<<N_EDGES / 8, 128, 0, stream>>>(ea, esrc, edst, P[5], P[6], x, 78, 0,
                                               AGG, 78);
  add_cvt_pad<<<CDIV(N_NODES * 96, 256), 256, 0, stream>>>(AGG, x, HB, N_NODES, 78, 96);
  gemm_bt<0><<<dim3(2, 512), 256, 0, stream>>>(HB, w11, P[5 + 3], nullptr, nullptr,
                                               UB, 96, 256, 0);
  gemm_bt<1><<<dim3(4, 512), 256, 0, stream>>>(UB, w12, P[5 + 5], bnS, bnS + 512,
                                               HB, 256, 512, 0);

  // ---- layers 2,3 (Cin=512, 2 channel-block passes of 256) ----
  for (int l = 1; l < 3; ++l) {
    int pb = 5 + 10 * l;
    u16* wa = (l == 1) ? w21 : w31;
    u16* wb = (l == 1) ? w22 : w31 == wa ? w32 : w32;  // w22 / w32
    wb = (l == 1) ? w22 : w32;
    for (int cb = 0; cb < 2; ++cb) {
      int c0 = cb * 256;
      hipMemsetAsync(AGG, 0, (size_t)N_NODES * 256 * 4, stream);
      edge_msg<0><<<N_EDGES / 8, 256, 0, stream>>>(ea, esrc, edst, P[pb] + c0 * 10,
                                                   P[pb + 1] + c0, HB, 512, c0, AGG,
                                                   256);
      add_cvt_ip<<<CDIV(N_NODES * 64, 256), 256, 0, stream>>>((const float4*)AGG, HB,
                                                              c0);
    }
    gemm_bt<0><<<dim3(4, 512), 256, 0, stream>>>(HB, wa, P[pb + 3], nullptr, nullptr,
                                                 UB, 512, 512, 0);
    gemm_bt<1><<<dim3(4, 512), 256, 0, stream>>>(UB, wb, P[pb + 5], bnS + 1024 * l,
                                                 bnS + 1024 * l + 512, HB, 512, 512, 0);
  }

  // ---- pool + head (head buffers live in AGGU, which is now free) ----
  pool_sum<<<N_GRAPHS, 512, 0, stream>>>(HB, start, gbuf);
  cvt_pad<<<CDIV(N_GRAPHS * 1504, 256), 256, 0, stream>>>(finger, fingb, N_GRAPHS,
                                                          1489, 1504);
  gemm_bt<0><<<dim3(2, 16), 256, 0, stream>>>(gbuf, wfcg, fcg_b, nullptr, nullptr,
                                              y0, 512, 512, 0);
  gemm_bt<0><<<dim3(1, 16), 256, 0, stream>>>(fingb, wfp1, fp1_b, nullptr, nullptr,
                                              fpa, 1504, 128, 0);
  gemm_bt<0><<<dim3(2, 16), 256, 0, stream>>>(fpa, wfp2, fp2_b, nullptr, nullptr,
                                              y0, 128, 512, 256);
  gemm_bt<0><<<dim3(2, 16), 256, 0, stream>>>(y0, wfb1, fb1_b, nullptr, nullptr,
                                              y1, 512, 256, 0);
  gemm_bt<0><<<dim3(1, 16), 256, 0, stream>>>(y1, wfb2, fb2_b, nullptr, nullptr,
                                              y2, 256, 128, 0);
  fb34<<<N_GRAPHS, 64, 0, stream>>>(y2, fb3_w, fb3_b, fb4_w, fb4_b, (float*)d_out);
}

// Round 3
// 669.704 us; speedup vs baseline: 1.6990x; 1.6990x over previous
//
#include <hip/hip_runtime.h>
#include <stdint.h>

typedef unsigned short u16;
typedef unsigned int u32;
typedef __bf16 bf16x8 __attribute__((ext_vector_type(8)));
typedef float f32x4 __attribute__((ext_vector_type(4)));

#define N_NODES 65536
#define N_EDGES 131072
#define N_GRAPHS 2048

static __device__ __forceinline__ float bf2f(u16 u) {
  union { u32 u; float f; } v; v.u = ((u32)u) << 16; return v.f;
}
static __device__ __forceinline__ u16 f2bf(float f) {
  union { float f; u32 u; } v; v.f = f;
  u32 r = v.u + 0x7fffu + ((v.u >> 16) & 1u);
  return (u16)(r >> 16);
}
static __device__ __forceinline__ void gl16(const void* g, void* l) {
  __builtin_amdgcn_global_load_lds(
      (__attribute__((address_space(1))) void*)(g),
      (__attribute__((address_space(3))) void*)(l), 16, 0, 0);
}

// ---------------------------------------------------------------------------
// bf16 GEMM, C[M][N] = epi(A[M][K] @ W[N][K]^T + bias).  128x128 tile, BK=32,
// 4 waves (2x2), each wave 64x64 via 4x4 mfma_f32_16x16x32_bf16 fragments.
// EPI 0: relu -> bf16.  EPI 1: relu -> bn affine (scale/shift) -> bf16.
// ---------------------------------------------------------------------------
template <int EPI>
__global__ __launch_bounds__(256) void gemm_bt(
    const u16* __restrict__ A, const u16* __restrict__ W,
    const float* __restrict__ bias, const float* __restrict__ scale,
    const float* __restrict__ shift, u16* __restrict__ Cp,
    int K, int ldc, int coff) {
  __shared__ u16 As[128 * 32];
  __shared__ u16 Bs[128 * 32];
  const int bm = blockIdx.y * 128;
  const int bn = blockIdx.x * 128;
  const int tid = threadIdx.x;
  const int lane = tid & 63;
  const int wid = tid >> 6;
  const int wr = wid >> 1, wc = wid & 1;
  const int lg = lane >> 4, lr = lane & 15;

  f32x4 acc[4][4];
#pragma unroll
  for (int i = 0; i < 4; ++i)
#pragma unroll
    for (int j = 0; j < 4; ++j) acc[i][j] = (f32x4){0.f, 0.f, 0.f, 0.f};

  const int srow = tid >> 2;
  const int c8 = (tid & 3) * 8;
  const u16* Ag0 = A + (size_t)(bm + srow) * K + c8;
  const u16* Ag1 = A + (size_t)(bm + 64 + srow) * K + c8;
  const u16* Wg0 = W + (size_t)(bn + srow) * K + c8;
  const u16* Wg1 = W + (size_t)(bn + 64 + srow) * K + c8;
  u16* lA0 = &As[tid * 8];
  u16* lA1 = &As[2048 + tid * 8];
  u16* lB0 = &Bs[tid * 8];
  u16* lB1 = &Bs[2048 + tid * 8];

  for (int k0 = 0; k0 < K; k0 += 32) {
    gl16(Ag0 + k0, lA0);
    gl16(Ag1 + k0, lA1);
    gl16(Wg0 + k0, lB0);
    gl16(Wg1 + k0, lB1);
    __syncthreads();  // drains vmcnt (global_load_lds) per compiler semantics
    bf16x8 af[4], bfv[4];
#pragma unroll
    for (int i = 0; i < 4; ++i)
      af[i] = *(const bf16x8*)&As[(wr * 64 + i * 16 + lr) * 32 + lg * 8];
#pragma unroll
    for (int j = 0; j < 4; ++j)
      bfv[j] = *(const bf16x8*)&Bs[(wc * 64 + j * 16 + lr) * 32 + lg * 8];
#pragma unroll
    for (int i = 0; i < 4; ++i)
#pragma unroll
      for (int j = 0; j < 4; ++j)
        acc[i][j] = __builtin_amdgcn_mfma_f32_16x16x32_bf16(af[i], bfv[j],
                                                            acc[i][j], 0, 0, 0);
    __syncthreads();
  }

#pragma unroll
  for (int i = 0; i < 4; ++i) {
#pragma unroll
    for (int j = 0; j < 4; ++j) {
#pragma unroll
      for (int r = 0; r < 4; ++r) {
        const int grow = bm + wr * 64 + i * 16 + lg * 4 + r;
        const int gcol = bn + wc * 64 + j * 16 + lr;
        float v = acc[i][j][r] + bias[gcol];
        v = fmaxf(v, 0.f);
        if (EPI == 1) v = v * scale[gcol] + shift[gcol];
        Cp[(size_t)grow * ldc + coff + gcol] = f2bf(v);
      }
    }
  }
}

// ---------------------------------------------------------------------------
// CSR build (edge list is static): deg histogram -> exclusive scan -> scatter.
// ---------------------------------------------------------------------------
__global__ void hist_deg(const int* __restrict__ dst, int* __restrict__ deg) {
  int e = blockIdx.x * blockDim.x + threadIdx.x;
  if (e < N_EDGES) atomicAdd(&deg[dst[e]], 1);
}

__global__ __launch_bounds__(1024) void scan_rowptr(const int* __restrict__ deg,
                                                    int* __restrict__ rowptr) {
  __shared__ int lds[1024];
  const int t = threadIdx.x;
  const int base = t * 64;
  int s = 0;
  for (int i = 0; i < 64; ++i) s += deg[base + i];
  lds[t] = s;
  __syncthreads();
  for (int ofs = 1; ofs < 1024; ofs <<= 1) {
    int v = (t >= ofs) ? lds[t - ofs] : 0;
    __syncthreads();
    lds[t] += v;
    __syncthreads();
  }
  int run = (t == 0) ? 0 : lds[t - 1];
  for (int i = 0; i < 64; ++i) {
    rowptr[base + i] = run;
    run += deg[base + i];
  }
  if (t == 1023) rowptr[65536] = run;
}

// consumes deg (countdown to zero); slot order within a node is arbitrary
__global__ void scatter_csr(const int* __restrict__ dst,
                            const int* __restrict__ rowptr,
                            int* __restrict__ deg, int* __restrict__ csr) {
  int e = blockIdx.x * blockDim.x + threadIdx.x;
  if (e >= N_EDGES) return;
  int d = dst[e];
  int pos = atomicSub(&deg[d], 1) - 1;
  csr[rowptr[d] + pos] = e;
}

// ---------------------------------------------------------------------------
// Node-centric fused aggregation (no atomics):
//   T[d][c] = bf16( h[d][c] + sum_{e: dst=d} relu( h[src[e]][c] + elin_e[c] ) )
// 128 threads x 4 channels = 512 channels; 8 nodes per block; edge-lin
// weights held in registers (40 VGPR/thread); ea rows are wave-uniform loads.
// ---------------------------------------------------------------------------
__global__ __launch_bounds__(128) void gather512(
    const int* __restrict__ rowptr, const int* __restrict__ csr,
    const int* __restrict__ esrc, const float* __restrict__ ea,
    const float* __restrict__ ew, const float* __restrict__ eb,
    const u16* __restrict__ H, u16* __restrict__ T) {
  const int t = threadIdx.x;
  const int c4 = t * 4;
  float w[4][10];
#pragma unroll
  for (int j = 0; j < 4; ++j)
#pragma unroll
    for (int k = 0; k < 10; ++k) w[j][k] = ew[(c4 + j) * 10 + k];
  float eb4[4];
#pragma unroll
  for (int j = 0; j < 4; ++j) eb4[j] = eb[c4 + j];

  const int dend = blockIdx.x * 8 + 8;
  for (int d = blockIdx.x * 8; d < dend; ++d) {
    uint2 hv = *(const uint2*)&H[(size_t)d * 512 + c4];
    float a0 = bf2f((u16)(hv.x & 0xffffu)), a1 = bf2f((u16)(hv.x >> 16));
    float a2 = bf2f((u16)(hv.y & 0xffffu)), a3 = bf2f((u16)(hv.y >> 16));
    const int i1 = rowptr[d + 1];
    for (int i = rowptr[d]; i < i1; ++i) {
      const int eid = csr[i];
      const int s = esrc[eid];
      const float2* eap = (const float2*)(ea + (size_t)eid * 10);
      float2 p0 = eap[0], p1 = eap[1], p2 = eap[2], p3 = eap[3], p4 = eap[4];
      const float ev[10] = {p0.x, p0.y, p1.x, p1.y, p2.x,
                            p2.y, p3.x, p3.y, p4.x, p4.y};
      uint2 hs = *(const uint2*)&H[(size_t)s * 512 + c4];
      float h0 = bf2f((u16)(hs.x & 0xffffu)), h1 = bf2f((u16)(hs.x >> 16));
      float h2 = bf2f((u16)(hs.y & 0xffffu)), h3 = bf2f((u16)(hs.y >> 16));
      float e0 = eb4[0], e1 = eb4[1], e2 = eb4[2], e3 = eb4[3];
#pragma unroll
      for (int k = 0; k < 10; ++k) {
        e0 += ev[k] * w[0][k];
        e1 += ev[k] * w[1][k];
        e2 += ev[k] * w[2][k];
        e3 += ev[k] * w[3][k];
      }
      a0 += fmaxf(h0 + e0, 0.f);
      a1 += fmaxf(h1 + e1, 0.f);
      a2 += fmaxf(h2 + e2, 0.f);
      a3 += fmaxf(h3 + e3, 0.f);
    }
    uint2 r;
    r.x = (u32)f2bf(a0) | ((u32)f2bf(a1) << 16);
    r.y = (u32)f2bf(a2) | ((u32)f2bf(a3) << 16);
    *(uint2*)&T[(size_t)d * 512 + c4] = r;
  }
}

// Layer-1 variant: X is f32 [N][78], T out bf16 [N][96] (zero-padded 78->96)
__global__ __launch_bounds__(128) void gather78(
    const int* __restrict__ rowptr, const int* __restrict__ csr,
    const int* __restrict__ esrc, const float* __restrict__ ea,
    const float* __restrict__ ew, const float* __restrict__ eb,
    const float* __restrict__ X, u16* __restrict__ T) {
  const int t = threadIdx.x;
  const bool act = t < 78;
  float w[10];
  float ebv = 0.f;
  if (act) {
#pragma unroll
    for (int k = 0; k < 10; ++k) w[k] = ew[t * 10 + k];
    ebv = eb[t];
  }
  const int dend = blockIdx.x * 8 + 8;
  for (int d = blockIdx.x * 8; d < dend; ++d) {
    float acc = act ? X[(size_t)d * 78 + t] : 0.f;
    const int i1 = rowptr[d + 1];
    for (int i = rowptr[d]; i < i1; ++i) {
      const int eid = csr[i];
      const int s = esrc[eid];
      const float2* eap = (const float2*)(ea + (size_t)eid * 10);
      float2 p0 = eap[0], p1 = eap[1], p2 = eap[2], p3 = eap[3], p4 = eap[4];
      const float ev[10] = {p0.x, p0.y, p1.x, p1.y, p2.x,
                            p2.y, p3.x, p3.y, p4.x, p4.y};
      if (act) {
        float el = ebv;
#pragma unroll
        for (int k = 0; k < 10; ++k) el += ev[k] * w[k];
        acc += fmaxf(X[(size_t)s * 78 + t] + el, 0.f);
      }
    }
    if (t < 96) T[(size_t)d * 96 + t] = act ? f2bf(acc) : (u16)0;
  }
}

// f32 -> bf16 with optional column padding (weights, finger)
__global__ void cvt_pad(const float* __restrict__ in, u16* __restrict__ out,
                        int rows, int cin, int cout) {
  int idx = blockIdx.x * blockDim.x + threadIdx.x;
  if (idx >= rows * cout) return;
  int rrow = idx / cout, j = idx - rrow * cout;
  out[idx] = (j < cin) ? f2bf(in[(size_t)rrow * cin + j]) : (u16)0;
}

// BN folded to per-channel affine
__global__ void bn_affine(const float* __restrict__ g, const float* __restrict__ b,
                          const float* __restrict__ m, const float* __restrict__ v,
                          float* __restrict__ scale, float* __restrict__ shift, int n) {
  int i = blockIdx.x * blockDim.x + threadIdx.x;
  if (i < n) {
    float s = g[i] * rsqrtf(v[i] + 1e-5f);
    scale[i] = s;
    shift[i] = b[i] - m[i] * s;
  }
}

// segment starts from sorted batch: start[g] = first node with batch >= g
__global__ void seg_starts(const int* __restrict__ batch, int* __restrict__ start,
                           int n, int ngraphs) {
  int i = blockIdx.x * blockDim.x + threadIdx.x;
  if (i >= n) return;
  int b = batch[i];
  int prev = (i == 0) ? -1 : batch[i - 1];
  for (int g = prev + 1; g <= b; ++g) start[g] = i;
  if (i == n - 1)
    for (int g = b + 1; g <= ngraphs; ++g) start[g] = n;
}

// global_add_pool (block per graph, thread per channel), bf16 in/out
__global__ void pool_sum(const u16* __restrict__ H, const int* __restrict__ start,
                         u16* __restrict__ g) {
  int gi = blockIdx.x, c = threadIdx.x;
  int s = start[gi], e = start[gi + 1];
  float acc = 0.f;
  for (int i = s; i < e; ++i) acc += bf2f(H[(size_t)i * 512 + c]);
  g[gi * 512 + c] = f2bf(acc);
}

// fb3 (relu) + fb4 + sigmoid, one block (64 threads) per graph row
__global__ void fb34(const u16* __restrict__ y2, const float* __restrict__ w3,
                     const float* __restrict__ b3, const float* __restrict__ w4,
                     const float* __restrict__ b4, float* __restrict__ out) {
  __shared__ float yr[128];
  __shared__ float h3[64];
  const int row = blockIdx.x, t = threadIdx.x;
  yr[t] = bf2f(y2[row * 128 + t]);
  yr[t + 64] = bf2f(y2[row * 128 + 64 + t]);
  __syncthreads();
  float s = b3[t];
  const float* w3r = &w3[t * 128];
#pragma unroll 8
  for (int k = 0; k < 128; ++k) s += yr[k] * w3r[k];
  h3[t] = fmaxf(s, 0.f);
  __syncthreads();
  if (t < 2) {
    float s4 = b4[t];
    const float* w4r = &w4[t * 64];
    for (int k = 0; k < 64; ++k) s4 += h3[k] * w4r[k];
    out[row * 2 + t] = 1.f / (1.f + expf(-s4));
  }
}

// ---------------------------------------------------------------------------
#define CDIV(a, b) (((a) + (b)-1) / (b))

extern "C" void kernel_launch(void* const* d_in, const int* in_sizes, int n_in,
                              void* d_out, int out_size, void* d_ws, size_t ws_size,
                              hipStream_t stream) {
  const float* x = (const float*)d_in[0];
  const float* finger = (const float*)d_in[1];
  const float* ea = (const float*)d_in[2];
  const int* eidx = (const int*)d_in[3];
  const int* batch = (const int*)d_in[4];
  const int* esrc = eidx;
  const int* edst = eidx + N_EDGES;

  const float* P[49];
  for (int i = 5; i < 49; ++i) P[i] = (const float*)d_in[i];
  // layer param base indices: l1=5, l2=15, l3=25
  // +0 ew, +1 eb, +2 w1, +3 b1, +4 w2, +5 b2, +6 bng, +7 bnb, +8 bnm, +9 bnv
  const float* fcg_w = P[35]; const float* fcg_b = P[36];
  const float* fp1_w = P[37]; const float* fp1_b = P[38];
  const float* fp2_w = P[39]; const float* fp2_b = P[40];
  const float* fb1_w = P[41]; const float* fb1_b = P[42];
  const float* fb2_w = P[43]; const float* fb2_b = P[44];
  const float* fb3_w = P[45]; const float* fb3_b = P[46];
  const float* fb4_w = P[47]; const float* fb4_b = P[48];

  // ---- workspace layout (~139 MB total) ----
  size_t off = 0;
  char* base = (char*)d_ws;
  auto alloc = [&](size_t bytes) -> void* {
    void* p = base + off;
    off = (off + bytes + 255) & ~(size_t)255;
    return p;
  };
  char* BA = (char*)alloc((size_t)N_NODES * 512 * 2);  // ping buffer (67 MB)
  char* BB = (char*)alloc((size_t)N_NODES * 512 * 2);  // pong buffer (67 MB)
  u16* w11 = (u16*)alloc(256 * 96 * 2);
  u16* w12 = (u16*)alloc(512 * 256 * 2);
  u16* w21 = (u16*)alloc(512 * 512 * 2);
  u16* w22 = (u16*)alloc(512 * 512 * 2);
  u16* w31 = (u16*)alloc(512 * 512 * 2);
  u16* w32 = (u16*)alloc(512 * 512 * 2);
  u16* wfcg = (u16*)alloc(256 * 512 * 2);
  u16* wfp1 = (u16*)alloc(128 * 1504 * 2);
  u16* wfp2 = (u16*)alloc(256 * 128 * 2);
  u16* wfb1 = (u16*)alloc(256 * 512 * 2);
  u16* wfb2 = (u16*)alloc(128 * 256 * 2);
  float* bnS = (float*)alloc(6 * 512 * 4);
  int* start = (int*)alloc(2049 * 4);
  int* deg = (int*)alloc(65536 * 4);
  int* rowptr = (int*)alloc(65537 * 4);
  int* csr = (int*)alloc(131072 * 4);
  if (off > ws_size) return;  // workspace insufficient; bail

  // head buffers carved from BA (free after the GNN layers)
  u16* fingb = (u16*)BA;                  // 2048*1504*2 = 6,160,384 B
  u16* gbuf = (u16*)(BA + 6160384);       // 2048*512*2  = 2,097,152 B
  u16* y0 = (u16*)(BA + 8257536);         // 2048*512*2  = 2,097,152 B
  u16* fpa = (u16*)(BA + 10354688);       // 2048*128*2  =   524,288 B
  u16* y1 = (u16*)(BA + 10878976);        // 2048*256*2  = 1,048,576 B
  u16* y2 = (u16*)(BA + 11927552);        // 2048*128*2  =   524,288 B

  // ---- parameter prep ----
  cvt_pad<<<CDIV(256 * 96, 256), 256, 0, stream>>>(P[5 + 2], w11, 256, 78, 96);
  cvt_pad<<<CDIV(512 * 256, 256), 256, 0, stream>>>(P[5 + 4], w12, 512, 256, 256);
  cvt_pad<<<CDIV(512 * 512, 256), 256, 0, stream>>>(P[15 + 2], w21, 512, 512, 512);
  cvt_pad<<<CDIV(512 * 512, 256), 256, 0, stream>>>(P[15 + 4], w22, 512, 512, 512);
  cvt_pad<<<CDIV(512 * 512, 256), 256, 0, stream>>>(P[25 + 2], w31, 512, 512, 512);
  cvt_pad<<<CDIV(512 * 512, 256), 256, 0, stream>>>(P[25 + 4], w32, 512, 512, 512);
  cvt_pad<<<CDIV(256 * 512, 256), 256, 0, stream>>>(fcg_w, wfcg, 256, 512, 512);
  cvt_pad<<<CDIV(128 * 1504, 256), 256, 0, stream>>>(fp1_w, wfp1, 128, 1489, 1504);
  cvt_pad<<<CDIV(256 * 128, 256), 256, 0, stream>>>(fp2_w, wfp2, 256, 128, 128);
  cvt_pad<<<CDIV(256 * 512, 256), 256, 0, stream>>>(fb1_w, wfb1, 256, 512, 512);
  cvt_pad<<<CDIV(128 * 256, 256), 256, 0, stream>>>(fb2_w, wfb2, 128, 256, 256);
  for (int l = 0; l < 3; ++l) {
    int pb = 5 + 10 * l;
    bn_affine<<<2, 256, 0, stream>>>(P[pb + 6], P[pb + 7], P[pb + 8], P[pb + 9],
                                     bnS + 1024 * l, bnS + 1024 * l + 512, 512);
  }
  seg_starts<<<CDIV(N_NODES, 256), 256, 0, stream>>>(batch, start, N_NODES, N_GRAPHS);

  // ---- CSR build (once; edge list is static) ----
  hipMemsetAsync(deg, 0, 65536 * 4, stream);
  hist_deg<<<CDIV(N_EDGES, 256), 256, 0, stream>>>(edst, deg);
  scan_rowptr<<<1, 1024, 0, stream>>>(deg, rowptr);
  scatter_csr<<<CDIV(N_EDGES, 256), 256, 0, stream>>>(edst, rowptr, deg, csr);

  // ---- layer 1 (Cin=78): T1->BB, U1->BA, H1->BB ----
  gather78<<<N_NODES / 8, 128, 0, stream>>>(rowptr, csr, esrc, ea, P[5], P[6], x,
                                            (u16*)BB);
  gemm_bt<0><<<dim3(2, 512), 256, 0, stream>>>((u16*)BB, w11, P[5 + 3], nullptr,
                                               nullptr, (u16*)BA, 96, 256, 0);
  gemm_bt<1><<<dim3(4, 512), 256, 0, stream>>>((u16*)BA, w12, P[5 + 5], bnS,
                                               bnS + 512, (u16*)BB, 256, 512, 0);

  // ---- layer 2: H1 in BB -> T2 in BA -> U2 in BB -> H2 in BA ----
  gather512<<<N_NODES / 8, 128, 0, stream>>>(rowptr, csr, esrc, ea, P[15], P[16],
                                             (const u16*)BB, (u16*)BA);
  gemm_bt<0><<<dim3(4, 512), 256, 0, stream>>>((u16*)BA, w21, P[15 + 3], nullptr,
                                               nullptr, (u16*)BB, 512, 512, 0);
  gemm_bt<1><<<dim3(4, 512), 256, 0, stream>>>((u16*)BB, w22, P[15 + 5],
                                               bnS + 1024, bnS + 1024 + 512,
                                               (u16*)BA, 512, 512, 0);

  // ---- layer 3: H2 in BA -> T3 in BB -> U3 in BA -> H3 in BB ----
  gather512<<<N_NODES / 8, 128, 0, stream>>>(rowptr, csr, esrc, ea, P[25], P[26],
                                             (const u16*)BA, (u16*)BB);
  gemm_bt<0><<<dim3(4, 512), 256, 0, stream>>>((u16*)BB, w31, P[25 + 3], nullptr,
                                               nullptr, (u16*)BA, 512, 512, 0);
  gemm_bt<1><<<dim3(4, 512), 256, 0, stream>>>((u16*)BA, w32, P[25 + 5],
                                               bnS + 2048, bnS + 2048 + 512,
                                               (u16*)BB, 512, 512, 0);

  // ---- pool + head (H3 in BB; head buffers live in BA, now free) ----
  pool_sum<<<N_GRAPHS, 512, 0, stream>>>((const u16*)BB, start, gbuf);
  cvt_pad<<<CDIV(N_GRAPHS * 1504, 256), 256, 0, stream>>>(finger, fingb, N_GRAPHS,
                                                          1489, 1504);
  gemm_bt<0><<<dim3(2, 16), 256, 0, stream>>>(gbuf, wfcg, fcg_b, nullptr, nullptr,
                                              y0, 512, 512, 0);
  gemm_bt<0><<<dim3(1, 16), 256, 0, stream>>>(fingb, wfp1, fp1_b, nullptr, nullptr,
                                              fpa, 1504, 128, 0);
  gemm_bt<0><<<dim3(2, 16), 256, 0, stream>>>(fpa, wfp2, fp2_b, nullptr, nullptr,
                                              y0, 128, 512, 256);
  gemm_bt<0><<<dim3(2, 16), 256, 0, stream>>>(y0, wfb1, fb1_b, nullptr, nullptr,
                                              y1, 512, 256, 0);
  gemm_bt<0><<<dim3(1, 16), 256, 0, stream>>>(y1, wfb2, fb2_b, nullptr, nullptr,
                                              y2, 256, 128, 0);
  fb34<<<N_GRAPHS, 64, 0, stream>>>(y2, fb3_w, fb3_b, fb4_w, fb4_b, (float*)d_out);
}

// Round 4
// 617.767 us; speedup vs baseline: 1.8418x; 1.0841x over previous
//
#include <hip/hip_runtime.h>
#include <stdint.h>

typedef unsigned short u16;
typedef unsigned int u32;
typedef __bf16 bf16x8 __attribute__((ext_vector_type(8)));
typedef float f32x4 __attribute__((ext_vector_type(4)));

#define N_NODES 65536
#define N_EDGES 131072
#define N_GRAPHS 2048

static __device__ __forceinline__ float bf2f(u16 u) {
  union { u32 u; float f; } v; v.u = ((u32)u) << 16; return v.f;
}
static __device__ __forceinline__ u16 f2bf(float f) {
  union { float f; u32 u; } v; v.f = f;
  u32 r = v.u + 0x7fffu + ((v.u >> 16) & 1u);
  return (u16)(r >> 16);
}
static __device__ __forceinline__ void gl16(const void* g, void* l) {
  __builtin_amdgcn_global_load_lds(
      (__attribute__((address_space(1))) void*)(g),
      (__attribute__((address_space(3))) void*)(l), 16, 0, 0);
}

// ---------------------------------------------------------------------------
// bf16 GEMM, C[M][N] = epi(A[M][K] @ W[N][K]^T + bias).  128x128 tile, BK=32,
// 4 waves (2x2), each wave 64x64 via 4x4 mfma_f32_16x16x32_bf16 fragments.
// XCD-aware bijective block swizzle (T1): same-A-panel blocks land on the
// same XCD so the panel is fetched from HBM once, served from L2 after.
// EPI 0: relu -> bf16.  EPI 1: relu -> bn affine (scale/shift) -> bf16.
// ---------------------------------------------------------------------------
template <int EPI>
__global__ __launch_bounds__(256) void gemm_bt(
    const u16* __restrict__ A, const u16* __restrict__ W,
    const float* __restrict__ bias, const float* __restrict__ scale,
    const float* __restrict__ shift, u16* __restrict__ Cp,
    int K, int ldc, int coff) {
  __shared__ u16 As[128 * 32];
  __shared__ u16 Bs[128 * 32];
  const u32 gx = gridDim.x;
  const u32 nwg = gx * gridDim.y;
  u32 lid = blockIdx.y * gx + blockIdx.x;
  if ((nwg & 7u) == 0u) {
    const u32 cpx = nwg >> 3;
    lid = (lid & 7u) * cpx + (lid >> 3);
  }
  const int bm = (int)(lid / gx) * 128;
  const int bn = (int)(lid % gx) * 128;
  const int tid = threadIdx.x;
  const int lane = tid & 63;
  const int wid = tid >> 6;
  const int wr = wid >> 1, wc = wid & 1;
  const int lg = lane >> 4, lr = lane & 15;

  f32x4 acc[4][4];
#pragma unroll
  for (int i = 0; i < 4; ++i)
#pragma unroll
    for (int j = 0; j < 4; ++j) acc[i][j] = (f32x4){0.f, 0.f, 0.f, 0.f};

  const int srow = tid >> 2;
  const int c8 = (tid & 3) * 8;
  const u16* Ag0 = A + (size_t)(bm + srow) * K + c8;
  const u16* Ag1 = A + (size_t)(bm + 64 + srow) * K + c8;
  const u16* Wg0 = W + (size_t)(bn + srow) * K + c8;
  const u16* Wg1 = W + (size_t)(bn + 64 + srow) * K + c8;
  u16* lA0 = &As[tid * 8];
  u16* lA1 = &As[2048 + tid * 8];
  u16* lB0 = &Bs[tid * 8];
  u16* lB1 = &Bs[2048 + tid * 8];

  for (int k0 = 0; k0 < K; k0 += 32) {
    gl16(Ag0 + k0, lA0);
    gl16(Ag1 + k0, lA1);
    gl16(Wg0 + k0, lB0);
    gl16(Wg1 + k0, lB1);
    __syncthreads();  // drains vmcnt (global_load_lds) per compiler semantics
    bf16x8 af[4], bfv[4];
#pragma unroll
    for (int i = 0; i < 4; ++i)
      af[i] = *(const bf16x8*)&As[(wr * 64 + i * 16 + lr) * 32 + lg * 8];
#pragma unroll
    for (int j = 0; j < 4; ++j)
      bfv[j] = *(const bf16x8*)&Bs[(wc * 64 + j * 16 + lr) * 32 + lg * 8];
#pragma unroll
    for (int i = 0; i < 4; ++i)
#pragma unroll
      for (int j = 0; j < 4; ++j)
        acc[i][j] = __builtin_amdgcn_mfma_f32_16x16x32_bf16(af[i], bfv[j],
                                                            acc[i][j], 0, 0, 0);
    __syncthreads();
  }

#pragma unroll
  for (int i = 0; i < 4; ++i) {
#pragma unroll
    for (int j = 0; j < 4; ++j) {
#pragma unroll
      for (int r = 0; r < 4; ++r) {
        const int grow = bm + wr * 64 + i * 16 + lg * 4 + r;
        const int gcol = bn + wc * 64 + j * 16 + lr;
        float v = acc[i][j][r] + bias[gcol];
        v = fmaxf(v, 0.f);
        if (EPI == 1) v = v * scale[gcol] + shift[gcol];
        Cp[(size_t)grow * ldc + coff + gcol] = f2bf(v);
      }
    }
  }
}

// ---------------------------------------------------------------------------
// CSR build (edge list is static): deg histogram -> exclusive scan -> scatter.
// ---------------------------------------------------------------------------
__global__ void hist_deg(const int* __restrict__ dst, int* __restrict__ deg) {
  int e = blockIdx.x * blockDim.x + threadIdx.x;
  if (e < N_EDGES) atomicAdd(&deg[dst[e]], 1);
}

__global__ __launch_bounds__(1024) void scan_rowptr(const int* __restrict__ deg,
                                                    int* __restrict__ rowptr) {
  __shared__ int lds[1024];
  const int t = threadIdx.x;
  const int base = t * 64;
  int s = 0;
  for (int i = 0; i < 64; ++i) s += deg[base + i];
  lds[t] = s;
  __syncthreads();
  for (int ofs = 1; ofs < 1024; ofs <<= 1) {
    int v = (t >= ofs) ? lds[t - ofs] : 0;
    __syncthreads();
    lds[t] += v;
    __syncthreads();
  }
  int run = (t == 0) ? 0 : lds[t - 1];
  for (int i = 0; i < 64; ++i) {
    rowptr[base + i] = run;
    run += deg[base + i];
  }
  if (t == 1023) rowptr[65536] = run;
}

// consumes deg (countdown to zero); slot order within a node is arbitrary
__global__ void scatter_csr(const int* __restrict__ dst,
                            const int* __restrict__ rowptr,
                            int* __restrict__ deg, int* __restrict__ csr) {
  int e = blockIdx.x * blockDim.x + threadIdx.x;
  if (e >= N_EDGES) return;
  int d = dst[e];
  int pos = atomicSub(&deg[d], 1) - 1;
  csr[rowptr[d] + pos] = e;
}

// ---------------------------------------------------------------------------
// Node-centric fused aggregation (no atomics):
//   T[d][c] = bf16( h[d][c] + sum_{e: dst=d} relu( h[src[e]][c] + elin_e[c] ) )
// ---------------------------------------------------------------------------
__global__ __launch_bounds__(128) void gather512(
    const int* __restrict__ rowptr, const int* __restrict__ csr,
    const int* __restrict__ esrc, const float* __restrict__ ea,
    const float* __restrict__ ew, const float* __restrict__ eb,
    const u16* __restrict__ H, u16* __restrict__ T) {
  const int t = threadIdx.x;
  const int c4 = t * 4;
  float w[4][10];
#pragma unroll
  for (int j = 0; j < 4; ++j)
#pragma unroll
    for (int k = 0; k < 10; ++k) w[j][k] = ew[(c4 + j) * 10 + k];
  float eb4[4];
#pragma unroll
  for (int j = 0; j < 4; ++j) eb4[j] = eb[c4 + j];

  const int dend = blockIdx.x * 8 + 8;
  for (int d = blockIdx.x * 8; d < dend; ++d) {
    uint2 hv = *(const uint2*)&H[(size_t)d * 512 + c4];
    float a0 = bf2f((u16)(hv.x & 0xffffu)), a1 = bf2f((u16)(hv.x >> 16));
    float a2 = bf2f((u16)(hv.y & 0xffffu)), a3 = bf2f((u16)(hv.y >> 16));
    const int i1 = rowptr[d + 1];
    for (int i = rowptr[d]; i < i1; ++i) {
      const int eid = csr[i];
      const int s = esrc[eid];
      const float2* eap = (const float2*)(ea + (size_t)eid * 10);
      float2 p0 = eap[0], p1 = eap[1], p2 = eap[2], p3 = eap[3], p4 = eap[4];
      const float ev[10] = {p0.x, p0.y, p1.x, p1.y, p2.x,
                            p2.y, p3.x, p3.y, p4.x, p4.y};
      uint2 hs = *(const uint2*)&H[(size_t)s * 512 + c4];
      float h0 = bf2f((u16)(hs.x & 0xffffu)), h1 = bf2f((u16)(hs.x >> 16));
      float h2 = bf2f((u16)(hs.y & 0xffffu)), h3 = bf2f((u16)(hs.y >> 16));
      float e0 = eb4[0], e1 = eb4[1], e2 = eb4[2], e3 = eb4[3];
#pragma unroll
      for (int k = 0; k < 10; ++k) {
        e0 += ev[k] * w[0][k];
        e1 += ev[k] * w[1][k];
        e2 += ev[k] * w[2][k];
        e3 += ev[k] * w[3][k];
      }
      a0 += fmaxf(h0 + e0, 0.f);
      a1 += fmaxf(h1 + e1, 0.f);
      a2 += fmaxf(h2 + e2, 0.f);
      a3 += fmaxf(h3 + e3, 0.f);
    }
    uint2 r;
    r.x = (u32)f2bf(a0) | ((u32)f2bf(a1) << 16);
    r.y = (u32)f2bf(a2) | ((u32)f2bf(a3) << 16);
    *(uint2*)&T[(size_t)d * 512 + c4] = r;
  }
}

// Layer-1 variant: X is f32 [N][78], T out bf16 [N][96] (zero-padded 78->96)
__global__ __launch_bounds__(128) void gather78(
    const int* __restrict__ rowptr, const int* __restrict__ csr,
    const int* __restrict__ esrc, const float* __restrict__ ea,
    const float* __restrict__ ew, const float* __restrict__ eb,
    const float* __restrict__ X, u16* __restrict__ T) {
  const int t = threadIdx.x;
  const bool act = t < 78;
  float w[10];
  float ebv = 0.f;
  if (act) {
#pragma unroll
    for (int k = 0; k < 10; ++k) w[k] = ew[t * 10 + k];
    ebv = eb[t];
  }
  const int dend = blockIdx.x * 8 + 8;
  for (int d = blockIdx.x * 8; d < dend; ++d) {
    float acc = act ? X[(size_t)d * 78 + t] : 0.f;
    const int i1 = rowptr[d + 1];
    for (int i = rowptr[d]; i < i1; ++i) {
      const int eid = csr[i];
      const int s = esrc[eid];
      const float2* eap = (const float2*)(ea + (size_t)eid * 10);
      float2 p0 = eap[0], p1 = eap[1], p2 = eap[2], p3 = eap[3], p4 = eap[4];
      const float ev[10] = {p0.x, p0.y, p1.x, p1.y, p2.x,
                            p2.y, p3.x, p3.y, p4.x, p4.y};
      if (act) {
        float el = ebv;
#pragma unroll
        for (int k = 0; k < 10; ++k) el += ev[k] * w[k];
        acc += fmaxf(X[(size_t)s * 78 + t] + el, 0.f);
      }
    }
    if (t < 96) T[(size_t)d * 96 + t] = act ? f2bf(acc) : (u16)0;
  }
}

// ---------------------------------------------------------------------------
// Consolidated prep: 11 f32->bf16 (pad) conversions in one launch.
// ---------------------------------------------------------------------------
struct CvtJob { const float* in; u16* out; int cin; int cout; };
struct CvtJobs { CvtJob j[11]; int blk_ofs[12]; };

__global__ __launch_bounds__(256) void cvt_multi(CvtJobs jb, int njobs) {
  int b = blockIdx.x;
  int ji = 0;
  while (ji + 1 < njobs && b >= jb.blk_ofs[ji + 1]) ++ji;
  const CvtJob J = jb.j[ji];
  int idx = (b - jb.blk_ofs[ji]) * 256 + threadIdx.x;
  // rows*cout bounded by blk_ofs spacing; guard via cout multiple-of-block pad
  int r = idx / J.cout, c = idx - r * J.cout;
  int tot_blocks = jb.blk_ofs[ji + 1] - jb.blk_ofs[ji];
  if (idx >= tot_blocks * 256) return;
  // exact element guard
  // (jobs sized so blocks*256 may overshoot; recompute rows bound)
  if (idx >= ((tot_blocks * 256) / J.cout) * J.cout && c >= J.cout) return;
  // safe row bound check using stored total elements in blk pad:
  J.out[idx] = (c < J.cin) ? f2bf(J.in[(size_t)r * J.cin + c]) : (u16)0;
}

// BN folded to per-channel affine, all 3 layers in one launch
struct BnJobs { const float* g[3]; const float* b[3]; const float* m[3];
                const float* v[3]; };
__global__ void bn_affine3(BnJobs p, float* __restrict__ bnS) {
  int i = blockIdx.x * blockDim.x + threadIdx.x;  // 0..1535
  int l = i >> 9, c = i & 511;
  float s = p.g[l][c] * rsqrtf(p.v[l][c] + 1e-5f);
  bnS[l * 1024 + c] = s;
  bnS[l * 1024 + 512 + c] = p.b[l][c] - p.m[l][c] * s;
}

// segment starts from sorted batch: start[g] = first node with batch >= g
__global__ void seg_starts(const int* __restrict__ batch, int* __restrict__ start,
                           int n, int ngraphs) {
  int i = blockIdx.x * blockDim.x + threadIdx.x;
  if (i >= n) return;
  int b = batch[i];
  int prev = (i == 0) ? -1 : batch[i - 1];
  for (int g = prev + 1; g <= b; ++g) start[g] = i;
  if (i == n - 1)
    for (int g = b + 1; g <= ngraphs; ++g) start[g] = n;
}

// plain f32 -> bf16 with column padding (finger, runs after GNN layers)
__global__ void cvt_pad(const float* __restrict__ in, u16* __restrict__ out,
                        int rows, int cin, int cout) {
  int idx = blockIdx.x * blockDim.x + threadIdx.x;
  if (idx >= rows * cout) return;
  int rrow = idx / cout, j = idx - rrow * cout;
  out[idx] = (j < cin) ? f2bf(in[(size_t)rrow * cin + j]) : (u16)0;
}

// global_add_pool (block per graph, thread per channel), bf16 in/out
__global__ void pool_sum(const u16* __restrict__ H, const int* __restrict__ start,
                         u16* __restrict__ g) {
  int gi = blockIdx.x, c = threadIdx.x;
  int s = start[gi], e = start[gi + 1];
  float acc = 0.f;
  for (int i = s; i < e; ++i) acc += bf2f(H[(size_t)i * 512 + c]);
  g[gi * 512 + c] = f2bf(acc);
}

// fb3 (relu) + fb4 + sigmoid, one block (64 threads) per graph row
__global__ void fb34(const u16* __restrict__ y2, const float* __restrict__ w3,
                     const float* __restrict__ b3, const float* __restrict__ w4,
                     const float* __restrict__ b4, float* __restrict__ out) {
  __shared__ float yr[128];
  __shared__ float h3[64];
  const int row = blockIdx.x, t = threadIdx.x;
  yr[t] = bf2f(y2[row * 128 + t]);
  yr[t + 64] = bf2f(y2[row * 128 + 64 + t]);
  __syncthreads();
  float s = b3[t];
  const float* w3r = &w3[t * 128];
#pragma unroll 8
  for (int k = 0; k < 128; ++k) s += yr[k] * w3r[k];
  h3[t] = fmaxf(s, 0.f);
  __syncthreads();
  if (t < 2) {
    float s4 = b4[t];
    const float* w4r = &w4[t * 64];
    for (int k = 0; k < 64; ++k) s4 += h3[k] * w4r[k];
    out[row * 2 + t] = 1.f / (1.f + expf(-s4));
  }
}

// ---------------------------------------------------------------------------
#define CDIV(a, b) (((a) + (b)-1) / (b))

extern "C" void kernel_launch(void* const* d_in, const int* in_sizes, int n_in,
                              void* d_out, int out_size, void* d_ws, size_t ws_size,
                              hipStream_t stream) {
  const float* x = (const float*)d_in[0];
  const float* finger = (const float*)d_in[1];
  const float* ea = (const float*)d_in[2];
  const int* eidx = (const int*)d_in[3];
  const int* batch = (const int*)d_in[4];
  const int* esrc = eidx;
  const int* edst = eidx + N_EDGES;

  const float* P[49];
  for (int i = 5; i < 49; ++i) P[i] = (const float*)d_in[i];
  const float* fcg_w = P[35]; const float* fcg_b = P[36];
  const float* fp1_w = P[37]; const float* fp1_b = P[38];
  const float* fp2_w = P[39]; const float* fp2_b = P[40];
  const float* fb1_w = P[41]; const float* fb1_b = P[42];
  const float* fb2_w = P[43]; const float* fb2_b = P[44];
  const float* fb3_w = P[45]; const float* fb3_b = P[46];
  const float* fb4_w = P[47]; const float* fb4_b = P[48];

  // ---- workspace layout (~139 MB total) ----
  size_t off = 0;
  char* base = (char*)d_ws;
  auto alloc = [&](size_t bytes) -> void* {
    void* p = base + off;
    off = (off + bytes + 255) & ~(size_t)255;
    return p;
  };
  char* BA = (char*)alloc((size_t)N_NODES * 512 * 2);  // ping buffer (67 MB)
  char* BB = (char*)alloc((size_t)N_NODES * 512 * 2);  // pong buffer (67 MB)
  u16* w11 = (u16*)alloc(256 * 96 * 2);
  u16* w12 = (u16*)alloc(512 * 256 * 2);
  u16* w21 = (u16*)alloc(512 * 512 * 2);
  u16* w22 = (u16*)alloc(512 * 512 * 2);
  u16* w31 = (u16*)alloc(512 * 512 * 2);
  u16* w32 = (u16*)alloc(512 * 512 * 2);
  u16* wfcg = (u16*)alloc(256 * 512 * 2);
  u16* wfp1 = (u16*)alloc(128 * 1504 * 2);
  u16* wfp2 = (u16*)alloc(256 * 128 * 2);
  u16* wfb1 = (u16*)alloc(256 * 512 * 2);
  u16* wfb2 = (u16*)alloc(128 * 256 * 2);
  float* bnS = (float*)alloc(6 * 512 * 4);
  int* start = (int*)alloc(2049 * 4);
  int* deg = (int*)alloc(65536 * 4);
  int* rowptr = (int*)alloc(65537 * 4);
  int* csr = (int*)alloc(131072 * 4);
  if (off > ws_size) return;  // workspace insufficient; bail

  // head buffers carved from BA (free after the GNN layers)
  u16* fingb = (u16*)BA;                  // 2048*1504*2 = 6,160,384 B
  u16* gbuf = (u16*)(BA + 6160384);       // 2048*512*2  = 2,097,152 B
  u16* y0 = (u16*)(BA + 8257536);         // 2048*512*2  = 2,097,152 B
  u16* fpa = (u16*)(BA + 10354688);       // 2048*128*2  =   524,288 B
  u16* y1 = (u16*)(BA + 10878976);        // 2048*256*2  = 1,048,576 B
  u16* y2 = (u16*)(BA + 11927552);        // 2048*128*2  =   524,288 B

  // ---- consolidated parameter prep (1 launch for 11 conversions) ----
  {
    CvtJobs jb;
    const float* ins[11] = {P[5 + 2], P[5 + 4], P[15 + 2], P[15 + 4], P[25 + 2],
                            P[25 + 4], fcg_w, fp1_w, fp2_w, fb1_w, fb2_w};
    u16* outs[11] = {w11, w12, w21, w22, w31, w32, wfcg, wfp1, wfp2, wfb1, wfb2};
    int rows[11] = {256, 512, 512, 512, 512, 512, 256, 128, 256, 256, 128};
    int cins[11] = {78, 256, 512, 512, 512, 512, 512, 1489, 128, 512, 256};
    int couts[11] = {96, 256, 512, 512, 512, 512, 512, 1504, 128, 512, 256};
    int acc = 0;
    for (int i = 0; i < 11; ++i) {
      jb.j[i].in = ins[i]; jb.j[i].out = outs[i];
      jb.j[i].cin = cins[i]; jb.j[i].cout = couts[i];
      jb.blk_ofs[i] = acc;
      acc += CDIV(rows[i] * couts[i], 256);
    }
    jb.blk_ofs[11] = acc;
    cvt_multi<<<acc, 256, 0, stream>>>(jb, 11);
  }
  {
    BnJobs bj;
    for (int l = 0; l < 3; ++l) {
      int pb = 5 + 10 * l;
      bj.g[l] = P[pb + 6]; bj.b[l] = P[pb + 7];
      bj.m[l] = P[pb + 8]; bj.v[l] = P[pb + 9];
    }
    bn_affine3<<<6, 256, 0, stream>>>(bj, bnS);
  }
  seg_starts<<<CDIV(N_NODES, 256), 256, 0, stream>>>(batch, start, N_NODES, N_GRAPHS);

  // ---- CSR build (once; edge list is static) ----
  hipMemsetAsync(deg, 0, 65536 * 4, stream);
  hist_deg<<<CDIV(N_EDGES, 256), 256, 0, stream>>>(edst, deg);
  scan_rowptr<<<1, 1024, 0, stream>>>(deg, rowptr);
  scatter_csr<<<CDIV(N_EDGES, 256), 256, 0, stream>>>(edst, rowptr, deg, csr);

  // ---- layer 1 (Cin=78): T1->BB, U1->BA, H1->BB ----
  gather78<<<N_NODES / 8, 128, 0, stream>>>(rowptr, csr, esrc, ea, P[5], P[6], x,
                                            (u16*)BB);
  gemm_bt<0><<<dim3(2, 512), 256, 0, stream>>>((u16*)BB, w11, P[5 + 3], nullptr,
                                               nullptr, (u16*)BA, 96, 256, 0);
  gemm_bt<1><<<dim3(4, 512), 256, 0, stream>>>((u16*)BA, w12, P[5 + 5], bnS,
                                               bnS + 512, (u16*)BB, 256, 512, 0);

  // ---- layer 2: H1 in BB -> T2 in BA -> U2 in BB -> H2 in BA ----
  gather512<<<N_NODES / 8, 128, 0, stream>>>(rowptr, csr, esrc, ea, P[15], P[16],
                                             (const u16*)BB, (u16*)BA);
  gemm_bt<0><<<dim3(4, 512), 256, 0, stream>>>((u16*)BA, w21, P[15 + 3], nullptr,
                                               nullptr, (u16*)BB, 512, 512, 0);
  gemm_bt<1><<<dim3(4, 512), 256, 0, stream>>>((u16*)BB, w22, P[15 + 5],
                                               bnS + 1024, bnS + 1024 + 512,
                                               (u16*)BA, 512, 512, 0);

  // ---- layer 3: H2 in BA -> T3 in BB -> U3 in BA -> H3 in BB ----
  gather512<<<N_NODES / 8, 128, 0, stream>>>(rowptr, csr, esrc, ea, P[25], P[26],
                                             (const u16*)BA, (u16*)BB);
  gemm_bt<0><<<dim3(4, 512), 256, 0, stream>>>((u16*)BB, w31, P[25 + 3], nullptr,
                                               nullptr, (u16*)BA, 512, 512, 0);
  gemm_bt<1><<<dim3(4, 512), 256, 0, stream>>>((u16*)BA, w32, P[25 + 5],
                                               bnS + 2048, bnS + 2048 + 512,
                                               (u16*)BB, 512, 512, 0);

  // ---- pool + head (H3 in BB; head buffers live in BA, now free) ----
  pool_sum<<<N_GRAPHS, 512, 0, stream>>>((const u16*)BB, start, gbuf);
  cvt_pad<<<CDIV(N_GRAPHS * 1504, 256), 256, 0, stream>>>(finger, fingb, N_GRAPHS,
                                                          1489, 1504);
  gemm_bt<0><<<dim3(2, 16), 256, 0, stream>>>(gbuf, wfcg, fcg_b, nullptr, nullptr,
                                              y0, 512, 512, 0);
  gemm_bt<0><<<dim3(1, 16), 256, 0, stream>>>(fingb, wfp1, fp1_b, nullptr, nullptr,
                                              fpa, 1504, 128, 0);
  gemm_bt<0><<<dim3(2, 16), 256, 0, stream>>>(fpa, wfp2, fp2_b, nullptr, nullptr,
                                              y0, 128, 512, 256);
  gemm_bt<0><<<dim3(2, 16), 256, 0, stream>>>(y0, wfb1, fb1_b, nullptr, nullptr,
                                              y1, 512, 256, 0);
  gemm_bt<0><<<dim3(1, 16), 256, 0, stream>>>(y1, wfb2, fb2_b, nullptr, nullptr,
                                              y2, 256, 128, 0);
  fb34<<<N_GRAPHS, 64, 0, stream>>>(y2, fb3_w, fb3_b, fb4_w, fb4_b, (float*)d_out);
}